// Round 3
// baseline (212.851 us; speedup 1.0000x reference)
//
#include <hip/hip_runtime.h>

#define B_    32
#define C_    512
#define HW2_  1024
#define NW    77
#define NP    80     // n padded to 80 (5 x 16 MFMA rows)
#define NPT   96     // n pitch for weT / P (3 K-steps of 32), cols >=77: P=0
#define WD    256

typedef unsigned int   uint32;
typedef unsigned short u16;
typedef __attribute__((ext_vector_type(8))) short bf16x8;  // MFMA A/B frag (4 VGPR)
typedef __attribute__((ext_vector_type(4))) float f32x4;   // MFMA C/D frag

#define MFMA(a, b, c) __builtin_amdgcn_mfma_f32_16x16x32_bf16(a, b, c, 0, 0, 0)

// element counts (bf16x8 units) for workspace planes
#define WE_ELN   ((size_t)B_ * NP * HW2_ / 8)   // 327680
#define WET_ELN  ((size_t)B_ * HW2_ * NPT / 8)  // 393216
#define W_ELN    ((size_t)HW2_ * WD / 8)        // 32768
#define E_ELN    ((size_t)B_ * NP * WD / 8)     // 81920

// fp32 -> (hi, lo) bf16 split. hi = truncation, residual exact, lo = RNE.
__device__ __forceinline__ void split1(float x, u16 &h, u16 &l) {
    uint32 u = __float_as_uint(x);
    h = (u16)(u >> 16);
    float r = x - __uint_as_float(u & 0xffff0000u);   // exact
    uint32 v = __float_as_uint(r);
    l = (u16)((v + 0x7fffu + ((v >> 16) & 1u)) >> 16);
}

__device__ __forceinline__ void split8(float4 a, float4 b, bf16x8 &h, bf16x8 &l) {
    float v[8] = {a.x, a.y, a.z, a.w, b.x, b.y, b.z, b.w};
    #pragma unroll
    for (int i = 0; i < 8; ++i) {
        u16 hh, ll; split1(v[i], hh, ll);
        h[i] = (short)hh; l[i] = (short)ll;
    }
}

// ---------------------------------------------------------------------------
// Kernel 0: one-shot hi/lo split of W_fc and word_emb (pads n to 80 w/ zeros).
// 448 blocks x 256 thr, one 8-float group per thread.
// ---------------------------------------------------------------------------
__global__ __launch_bounds__(256) void split_pre(
    const float* __restrict__ W_fc, const float* __restrict__ word_emb,
    bf16x8* __restrict__ Wh, bf16x8* __restrict__ Wl,
    bf16x8* __restrict__ Eh, bf16x8* __restrict__ El)
{
    const int g = blockIdx.x * 256 + threadIdx.x;
    if (g < (int)W_ELN) {                       // W_fc: 1024x256
        float4 x = *(const float4*)(W_fc + g * 8);
        float4 y = *(const float4*)(W_fc + g * 8 + 4);
        bf16x8 h, l; split8(x, y, h, l);
        Wh[g] = h; Wl[g] = l;
    } else {
        const int e = g - (int)W_ELN;           // word_emb: [32][80][256] padded
        const int b = e / 2560, r = e % 2560;   // 80*32 groups per batch
        const int n = r >> 5, gg = r & 31;
        bf16x8 h = (bf16x8)(short)0, l = h;
        if (n < NW) {
            const float* p = word_emb + ((size_t)(b * NW + n)) * WD + gg * 8;
            float4 x = *(const float4*)p, y = *(const float4*)(p + 4);
            split8(x, y, h, l);
        }
        Eh[e] = h; El[e] = l;
    }
}

// ---------------------------------------------------------------------------
// Kernel 1: we = word_emb @ W_fc^T + b_fc via MFMA, pre-split bf16 inputs.
// Pure load+MFMA main loop (no VALU splitting). Packed u32 hi|lo LDS tile
// feeds both output layouts without re-splitting.
// grid 512, b = (id&7)+8*(id>>7) so batch b lands on XCD b%8 (matches attn).
// ---------------------------------------------------------------------------
__global__ __launch_bounds__(256, 2) void we_gemm(
    const bf16x8* __restrict__ Wh, const bf16x8* __restrict__ Wl,
    const bf16x8* __restrict__ Eh, const bf16x8* __restrict__ El,
    const float* __restrict__ b_fc,
    bf16x8* __restrict__ we_hi, bf16x8* __restrict__ we_lo,
    bf16x8* __restrict__ weT_hi, bf16x8* __restrict__ weT_lo)
{
    __shared__ __align__(16) uint32 HL[NP][68];   // (hi<<16)|lo, 21.8 KB

    const int id = blockIdx.x;
    const int b  = (id & 7) + 8 * (id >> 7);      // XCD = id%8 = b%8
    const int kb = ((id >> 3) & 15) * 64;
    const int t  = threadIdx.x;
    const int w  = t >> 6, lane = t & 63, lr = lane & 15, lg = lane >> 4;
    const int kout = kb + 16 * w + lr;

    f32x4 acc[5];
    #pragma unroll
    for (int m = 0; m < 5; ++m) acc[m] = (f32x4)0.0f;

    const bf16x8* wrh = Wh + kout * 32;           // row = 256 f = 32 groups
    const bf16x8* wrl = Wl + kout * 32;
    const bf16x8* ebh = Eh + (b * NP + lr) * 32;
    const bf16x8* ebl = El + (b * NP + lr) * 32;

    #pragma unroll
    for (int ks = 0; ks < 8; ++ks) {
        const int o = ks * 4 + lg;
        const bf16x8 bh = wrh[o], bl = wrl[o];
        #pragma unroll
        for (int m = 0; m < 5; ++m) {
            const bf16x8 ah = ebh[m * 512 + o];   // 16 rows * 32 groups
            const bf16x8 al = ebl[m * 512 + o];
            acc[m] = MFMA(ah, bh, acc[m]);
            acc[m] = MFMA(ah, bl, acc[m]);
            acc[m] = MFMA(al, bh, acc[m]);
            acc[m] = MFMA(al, bl, acc[m]);        // 4-term: we must be accurate
        }
    }

    const float bias = b_fc[kout];
    #pragma unroll
    for (int m = 0; m < 5; ++m)
        #pragma unroll
        for (int r = 0; r < 4; ++r) {
            u16 hh, ll; split1(acc[m][r] + bias, hh, ll);
            HL[16 * m + 4 * lg + r][16 * w + lr] = ((uint32)hh << 16) | ll;
        }
    __syncthreads();

    // we_hi/lo [b][n][kb..kb+64]
    #pragma unroll
    for (int u0 = 0; u0 < 640; u0 += 256) {
        const int u = u0 + t;
        if (u < 640) {
            const int n = u >> 3, c8 = (u & 7) * 8;
            uint4 p0 = *(const uint4*)&HL[n][c8];
            uint4 p1 = *(const uint4*)&HL[n][c8 + 4];
            const uint32 pw[8] = {p0.x, p0.y, p0.z, p0.w, p1.x, p1.y, p1.z, p1.w};
            bf16x8 hv, lv;
            #pragma unroll
            for (int i = 0; i < 8; ++i) {
                hv[i] = (short)(pw[i] >> 16);
                lv[i] = (short)(pw[i] & 0xffffu);
            }
            const int o = ((b * NP + n) * HW2_ + kb + c8) >> 3;
            we_hi[o] = hv; we_lo[o] = lv;
        }
    }
    // weT_hi/lo [b][kout][n] pitch 96; n>=80 written 0 (P is 0 there anyway).
    if (t < 128) {
        const int kr = t & 63, sel = t >> 6;
        bf16x8* dst = (sel ? weT_lo : weT_hi) + (((b * HW2_ + kb + kr) * NPT) >> 3);
        #pragma unroll
        for (int g = 0; g < 12; ++g) {
            bf16x8 v;
            #pragma unroll
            for (int i = 0; i < 8; ++i) {
                const int n = g * 8 + i;
                const uint32 p = (n < NP) ? HL[n][kr] : 0u;
                v[i] = (short)(sel ? (p & 0xffffu) : (p >> 16));
            }
            dst[g] = v;
        }
    }
}

// ---------------------------------------------------------------------------
// Kernel 2: fused scores^T -> softmax -> out via MFMA (3-term split).
// Explicit register double-buffering: phase 1 prefetches iter+1's feat + we
// fragments; phase 3 runs a 2-deep 3-slot ring on weT pairs. All-wave softmax.
// ---------------------------------------------------------------------------
__global__ __launch_bounds__(256, 3) void attn_mfma(
    const float* __restrict__ feat,
    const bf16x8* __restrict__ we_hi, const bf16x8* __restrict__ we_lo,
    const bf16x8* __restrict__ weT_hi, const bf16x8* __restrict__ weT_lo,
    float* __restrict__ out)
{
    __shared__ __align__(16) float S[4][16][84];  // partial scores (21.5 KB)
    __shared__ __align__(16) u16   Ph[16][NPT];   // P hi (3 KB)
    __shared__ __align__(16) u16   Pl[16][NPT];   // P lo (3 KB)

    const int id  = blockIdx.x;
    const int b   = (id & 7) + 8 * (id >> 8);     // batch -> XCD id&7 (=b%8)
    const int c0  = ((id >> 3) & 31) * 16;        // strip's 16 c rows

    const int t    = threadIdx.x;
    const int h    = t >> 6;                      // wave = K-quarter
    const int lane = t & 63, lr = lane & 15, lg = lane >> 4;

    // ---- Phase 1: scores^T[n][c] = we . f^T, 1-deep register prefetch -----
    f32x4 acc[5];
    #pragma unroll
    for (int m = 0; m < 5; ++m) acc[m] = (f32x4)0.0f;

    const float*  frow = feat + (size_t)(b * C_ + c0 + lr) * HW2_;
    const bf16x8* wh   = we_hi + (size_t)b * (NP * HW2_ / 8);
    const bf16x8* wl   = we_lo + (size_t)b * (NP * HW2_ / 8);

    float4 fx[2], fy[2];
    bf16x8 AH[2][5], AL[2][5];

#define P1_LOAD(slot, ksv) do {                                   \
        const int kk_ = h * 256 + (ksv) * 32 + 8 * lg;            \
        fx[slot] = *(const float4*)(frow + kk_);                  \
        fy[slot] = *(const float4*)(frow + kk_ + 4);              \
        const int go_ = h * 32 + (ksv) * 4 + lg;                  \
        _Pragma("unroll")                                         \
        for (int m_ = 0; m_ < 5; ++m_) {                          \
            AH[slot][m_] = wh[(16 * m_ + lr) * 128 + go_];        \
            AL[slot][m_] = wl[(16 * m_ + lr) * 128 + go_];        \
        } } while (0)

    P1_LOAD(0, 0);
    #pragma unroll
    for (int ks = 0; ks < 8; ++ks) {
        if (ks < 7) {
            if ((ks & 1) == 0) P1_LOAD(1, ks + 1);
            else               P1_LOAD(0, ks + 1);
        }
        const int cur = ks & 1;
        bf16x8 fh, fl; split8(fx[cur], fy[cur], fh, fl);
        #pragma unroll
        for (int m = 0; m < 5; ++m) {
            acc[m] = MFMA(AH[cur][m], fh, acc[m]);
            acc[m] = MFMA(AH[cur][m], fl, acc[m]);
            acc[m] = MFMA(AL[cur][m], fh, acc[m]);
        }
    }
#undef P1_LOAD

    #pragma unroll
    for (int m = 0; m < 5; ++m)
        #pragma unroll
        for (int r = 0; r < 4; ++r)
            S[h][lr][16 * m + 4 * lg + r] = acc[m][r];
    __syncthreads();

    // ---- softmax over n, all waves: wave h owns rows 4h..4h+3 -------------
    {
        const int srow = 4 * h + (lane >> 4), scol = lane & 15;
        float v5[6];
        float mx = -3.0e38f;
        #pragma unroll
        for (int j = 0; j < 6; ++j) {
            const int n = scol + 16 * j;
            float sv = 0.f;
            if (j < 5) {
                sv = S[0][srow][n] + S[1][srow][n] + S[2][srow][n] + S[3][srow][n];
                if (n < NW) mx = fmaxf(mx, sv);
            }
            v5[j] = sv;
        }
        mx = fmaxf(mx, __shfl_xor(mx, 1));
        mx = fmaxf(mx, __shfl_xor(mx, 2));
        mx = fmaxf(mx, __shfl_xor(mx, 4));
        mx = fmaxf(mx, __shfl_xor(mx, 8));
        float sum = 0.f;
        #pragma unroll
        for (int j = 0; j < 6; ++j) {
            const int n = scol + 16 * j;
            const float e = (n < NW) ? __expf(v5[j] - mx) : 0.f;
            v5[j] = e; sum += e;
        }
        sum += __shfl_xor(sum, 1);
        sum += __shfl_xor(sum, 2);
        sum += __shfl_xor(sum, 4);
        sum += __shfl_xor(sum, 8);
        const float inv = 1.0f / sum;
        #pragma unroll
        for (int j = 0; j < 6; ++j) {
            const int n = scol + 16 * j;
            u16 ph, pl; split1(v5[j] * inv, ph, pl);
            Ph[srow][n] = ph; Pl[srow][n] = pl;
        }
    }
    __syncthreads();

    // ---- Phase 3: out^T[kout][c] = weT . P^T; 2-deep 3-slot weT ring ------
    bf16x8 pbh[3], pbl[3];
    #pragma unroll
    for (int ksn = 0; ksn < 3; ++ksn) {
        pbh[ksn] = *(const bf16x8*)&Ph[lr][32 * ksn + 8 * lg];
        pbl[ksn] = *(const bf16x8*)&Pl[lr][32 * ksn + 8 * lg];
    }
    const bf16x8* th = weT_hi + (size_t)b * (HW2_ * NPT / 8);
    const bf16x8* tl = weT_lo + (size_t)b * (HW2_ * NPT / 8);
    float* orow = out + (size_t)(b * C_ + c0 + lr) * HW2_;

    bf16x8 WA[3], WB[3];

#define P3_LOAD(slot, g) do {                                     \
        const int ci_ = (g) / 12, s_ = (g) % 12;                  \
        const int kt_ = s_ & 3, ksn_ = s_ >> 2;                   \
        const int row_ = (ci_ * 4 + h) * 64 + 16 * kt_ + lr;      \
        const int off_ = row_ * 12 + 4 * ksn_ + lg;               \
        WA[slot] = th[off_]; WB[slot] = tl[off_]; } while (0)

    P3_LOAD(0, 0);
    P3_LOAD(1, 1);
    #pragma unroll
    for (int ci = 0; ci < 4; ++ci) {
        f32x4 o[4];
        #pragma unroll
        for (int kt = 0; kt < 4; ++kt) o[kt] = (f32x4)0.0f;
        #pragma unroll
        for (int s = 0; s < 12; ++s) {
            const int g = ci * 12 + s;
            if (g < 46) {
                const int sl = (g + 2) % 3;
                if (sl == 0)      P3_LOAD(0, g + 2);
                else if (sl == 1) P3_LOAD(1, g + 2);
                else              P3_LOAD(2, g + 2);
            }
            const int cs = g % 3, kt = s & 3, ksn = s >> 2;
            o[kt] = MFMA(WA[cs], pbh[ksn], o[kt]);
            o[kt] = MFMA(WA[cs], pbl[ksn], o[kt]);
            o[kt] = MFMA(WB[cs], pbh[ksn], o[kt]);
        }
        const int kb2 = (ci * 4 + h) * 64;
        #pragma unroll
        for (int kt = 0; kt < 4; ++kt) {
            float4 v = make_float4(o[kt][0], o[kt][1], o[kt][2], o[kt][3]);
            *(float4*)(orow + kb2 + 16 * kt + 4 * lg) = v;
        }
    }
#undef P3_LOAD
}

// ---------------------------------------------------------------------------
extern "C" void kernel_launch(void* const* d_in, const int* in_sizes, int n_in,
                              void* d_out, int out_size, void* d_ws, size_t ws_size,
                              hipStream_t stream) {
    (void)in_sizes; (void)n_in; (void)out_size; (void)ws_size;
    const float* feat     = (const float*)d_in[0];
    const float* word_emb = (const float*)d_in[1];
    const float* W_fc     = (const float*)d_in[2];
    const float* b_fc     = (const float*)d_in[3];

    // workspace: 26.7 MB of bf16 hi/lo planes (element = bf16x8 = 16 B)
    bf16x8* we_hi  = (bf16x8*)d_ws;
    bf16x8* we_lo  = we_hi  + WE_ELN;
    bf16x8* weT_hi = we_lo  + WE_ELN;
    bf16x8* weT_lo = weT_hi + WET_ELN;
    bf16x8* Wh     = weT_lo + WET_ELN;
    bf16x8* Wl     = Wh + W_ELN;
    bf16x8* Eh     = Wl + W_ELN;
    bf16x8* El     = Eh + E_ELN;

    split_pre<<<448, 256, 0, stream>>>(W_fc, word_emb, Wh, Wl, Eh, El);
    we_gemm<<<512, 256, 0, stream>>>(Wh, Wl, Eh, El, b_fc, we_hi, we_lo, weT_hi, weT_lo);
    attn_mfma<<<1024, 256, 0, stream>>>(feat, we_hi, we_lo, weT_hi, weT_lo, (float*)d_out);
}

// Round 4
// 182.132 us; speedup vs baseline: 1.1687x; 1.1687x over previous
//
#include <hip/hip_runtime.h>

#define B_    32
#define C_    512
#define HW2_  1024
#define NW    77
#define NP    80     // n padded to 80 (5 x 16 MFMA rows)
#define NPT   96     // n pitch for weT / P (3 K-steps of 32), cols >=77: P=0
#define WD    256

typedef unsigned int   uint32;
typedef unsigned short u16;
typedef __attribute__((ext_vector_type(8))) short bf16x8;  // MFMA A/B frag (4 VGPR)
typedef __attribute__((ext_vector_type(4))) float f32x4;   // MFMA C/D frag

#define MFMA(a, b, c) __builtin_amdgcn_mfma_f32_16x16x32_bf16(a, b, c, 0, 0, 0)

// workspace element counts (bf16x8 = 16 B units)
// we planes:  [b][q=16][n=80][kloc=64]  -> idx = ((b*16+q)*80+n)*8 + kloc/8
// weT planes: [b][kout=1024][n=96]      -> idx = (b*1024+kout)*12 + n/8
// Wh/Wl:      [kout=1024][d=256]        -> idx = kout*32 + d/8
// Eh/El:      [b][n=80][d=256]          -> idx = (b*80+n)*32 + d/8
#define WE_ELN   ((size_t)B_ * 16 * NP * 8)     // 327680
#define WET_ELN  ((size_t)B_ * HW2_ * 12)       // 393216
#define W_ELN    ((size_t)HW2_ * 32)            // 32768
#define E_ELN    ((size_t)B_ * NP * 32)         // 81920

// fp32 -> (hi, lo) bf16 split. hi = truncation, residual exact, lo = RNE.
__device__ __forceinline__ void split1(float x, u16 &h, u16 &l) {
    uint32 u = __float_as_uint(x);
    h = (u16)(u >> 16);
    float r = x - __uint_as_float(u & 0xffff0000u);   // exact
    uint32 v = __float_as_uint(r);
    l = (u16)((v + 0x7fffu + ((v >> 16) & 1u)) >> 16);
}

__device__ __forceinline__ void split8(float4 a, float4 b, bf16x8 &h, bf16x8 &l) {
    float v[8] = {a.x, a.y, a.z, a.w, b.x, b.y, b.z, b.w};
    #pragma unroll
    for (int i = 0; i < 8; ++i) {
        u16 hh, ll; split1(v[i], hh, ll);
        h[i] = (short)hh; l[i] = (short)ll;
    }
}

// ---------------------------------------------------------------------------
// Kernel 0: one-shot hi/lo split of W_fc and word_emb (pads n to 80 w/ zeros).
// ---------------------------------------------------------------------------
__global__ __launch_bounds__(256) void split_pre(
    const float* __restrict__ W_fc, const float* __restrict__ word_emb,
    bf16x8* __restrict__ Wh, bf16x8* __restrict__ Wl,
    bf16x8* __restrict__ Eh, bf16x8* __restrict__ El)
{
    const int g = blockIdx.x * 256 + threadIdx.x;
    if (g < (int)W_ELN) {                       // W_fc: 1024x256
        float4 x = *(const float4*)(W_fc + g * 8);
        float4 y = *(const float4*)(W_fc + g * 8 + 4);
        bf16x8 h, l; split8(x, y, h, l);
        Wh[g] = h; Wl[g] = l;
    } else {
        const int e = g - (int)W_ELN;           // word_emb: [32][80][256] padded
        const int b = e / 2560, r = e % 2560;
        const int n = r >> 5, gg = r & 31;
        bf16x8 h = (bf16x8)(short)0, l = h;
        if (n < NW) {
            const float* p = word_emb + ((size_t)(b * NW + n)) * WD + gg * 8;
            float4 x = *(const float4*)p, y = *(const float4*)(p + 4);
            split8(x, y, h, l);
        }
        Eh[e] = h; El[e] = l;
    }
}

// ---------------------------------------------------------------------------
// Kernel 1: we = word_emb @ W_fc^T + b_fc via MFMA, pre-split bf16 inputs.
// Outputs both layouts with FULLY CONTIGUOUS stores.
// grid 512 = 32 b x 16 k-chunks, b -> XCD b%8 (matches attn).
// ---------------------------------------------------------------------------
__global__ __launch_bounds__(256) void we_gemm(
    const bf16x8* __restrict__ Wh, const bf16x8* __restrict__ Wl,
    const bf16x8* __restrict__ Eh, const bf16x8* __restrict__ El,
    const float* __restrict__ b_fc,
    bf16x8* __restrict__ we_hi, bf16x8* __restrict__ we_lo,
    bf16x8* __restrict__ weT_hi, bf16x8* __restrict__ weT_lo)
{
    __shared__ __align__(16) uint32 HL[NP][68];   // (hi<<16)|lo, 21.8 KB

    const int id = blockIdx.x;
    const int b  = (id & 7) + 8 * (id >> 7);      // XCD = id%8 = b%8
    const int q  = (id >> 3) & 15;
    const int kb = q * 64;
    const int t  = threadIdx.x;
    const int w  = t >> 6, lane = t & 63, lr = lane & 15, lg = lane >> 4;
    const int kout = kb + 16 * w + lr;

    f32x4 acc[5];
    #pragma unroll
    for (int m = 0; m < 5; ++m) acc[m] = (f32x4)0.0f;

    const bf16x8* wrh = Wh + kout * 32;
    const bf16x8* wrl = Wl + kout * 32;
    const bf16x8* ebh = Eh + (b * NP + lr) * 32;
    const bf16x8* ebl = El + (b * NP + lr) * 32;

    #pragma unroll
    for (int ks = 0; ks < 8; ++ks) {
        const int o = ks * 4 + lg;
        const bf16x8 bh = wrh[o], bl = wrl[o];
        #pragma unroll
        for (int m = 0; m < 5; ++m) {
            const bf16x8 ah = ebh[m * 512 + o];
            const bf16x8 al = ebl[m * 512 + o];
            acc[m] = MFMA(ah, bh, acc[m]);
            acc[m] = MFMA(ah, bl, acc[m]);
            acc[m] = MFMA(al, bh, acc[m]);
            acc[m] = MFMA(al, bl, acc[m]);
        }
    }

    const float bias = b_fc[kout];
    #pragma unroll
    for (int m = 0; m < 5; ++m)
        #pragma unroll
        for (int r = 0; r < 4; ++r) {
            u16 hh, ll; split1(acc[m][r] + bias, hh, ll);
            HL[16 * m + 4 * lg + r][16 * w + lr] = ((uint32)hh << 16) | ll;
        }
    __syncthreads();

    // we planes: [b][q][n][64k] -> contiguous 10 KB run per plane per block
    #pragma unroll
    for (int u0 = 0; u0 < 640; u0 += 256) {
        const int u = u0 + t;
        if (u < 640) {
            const int n = u >> 3, c8 = (u & 7) * 8;
            uint4 p0 = *(const uint4*)&HL[n][c8];
            uint4 p1 = *(const uint4*)&HL[n][c8 + 4];
            const uint32 pw[8] = {p0.x, p0.y, p0.z, p0.w, p1.x, p1.y, p1.z, p1.w};
            bf16x8 hv, lv;
            #pragma unroll
            for (int i = 0; i < 8; ++i) {
                hv[i] = (short)(pw[i] >> 16);
                lv[i] = (short)(pw[i] & 0xffffu);
            }
            const int o = ((b * 16 + q) * NP + n) * 8 + (u & 7);
            we_hi[o] = hv; we_lo[o] = lv;
        }
    }
    // weT planes: [b][kout][96] -> consecutive threads write consecutive 16 B
    #pragma unroll
    for (int v0 = 0; v0 < 1536; v0 += 256) {
        const int v = v0 + t;
        const int sel = v >= 768;
        const int r2  = sel ? v - 768 : v;
        const int row = r2 / 12, g = r2 % 12;
        bf16x8 val;
        #pragma unroll
        for (int i = 0; i < 8; ++i) {
            const int n = g * 8 + i;
            const uint32 p = (n < NP) ? HL[n][row] : 0u;
            val[i] = (short)(sel ? (p & 0xffffu) : (p >> 16));
        }
        (sel ? weT_lo : weT_hi)[(b * HW2_ + kb + row) * 12 + g] = val;
    }
}

// ---------------------------------------------------------------------------
// Kernel 2: fused scores^T -> softmax -> out via MFMA (3-term split).
// Block = 32 c-rows (2 strips per wave), 4 waves = 4 K-quarters.
// grid 512 = 32 b x 16 c-blocks -> 2 blocks/CU; XCD-swizzled per batch.
// ---------------------------------------------------------------------------
__global__ __launch_bounds__(256, 2) void attn_mfma(
    const float* __restrict__ feat,
    const bf16x8* __restrict__ we_hi, const bf16x8* __restrict__ we_lo,
    const bf16x8* __restrict__ weT_hi, const bf16x8* __restrict__ weT_lo,
    float* __restrict__ out)
{
    __shared__ __align__(16) float S[4][16][84];  // partial scores (21.5 KB)
    __shared__ __align__(16) u16   Ph[32][NPT];   // P hi (6 KB)
    __shared__ __align__(16) u16   Pl[32][NPT];   // P lo (6 KB)

    const int id  = blockIdx.x;
    const int b   = (id & 7) + 8 * (id >> 7);     // batch -> XCD id&7 (=b%8)
    const int c0  = ((id >> 3) & 15) * 32;        // block's 32 c rows

    const int t    = threadIdx.x;
    const int h    = t >> 6;                      // wave = K-quarter
    const int lane = t & 63, lr = lane & 15, lg = lane >> 4;

    // ---- Phase 1: scores^T[n][c] for 2 c-strips, K quarter per wave -------
    f32x4 acc[2][5];
    #pragma unroll
    for (int s = 0; s < 2; ++s)
        #pragma unroll
        for (int m = 0; m < 5; ++m) acc[s][m] = (f32x4)0.0f;

    const float* frow0 = feat + (size_t)(b * C_ + c0 + lr) * HW2_;
    const float* frow1 = frow0 + 16 * HW2_;

    #pragma unroll
    for (int ks = 0; ks < 8; ++ks) {
        const int kk = h * 256 + ks * 32 + 8 * lg;
        bf16x8 fh0, fl0, fh1, fl1;
        {   float4 x = *(const float4*)(frow0 + kk);
            float4 y = *(const float4*)(frow0 + kk + 4);
            split8(x, y, fh0, fl0); }
        {   float4 x = *(const float4*)(frow1 + kk);
            float4 y = *(const float4*)(frow1 + kk + 4);
            split8(x, y, fh1, fl1); }
        const int qb  = (b * 16 + h * 4 + (ks >> 1)) * NP;
        const int sub = (ks & 1) * 4 + lg;
        #pragma unroll
        for (int m = 0; m < 5; ++m) {
            const int o = (qb + 16 * m + lr) * 8 + sub;
            const bf16x8 ah = we_hi[o];
            const bf16x8 al = we_lo[o];
            acc[0][m] = MFMA(ah, fh0, acc[0][m]);
            acc[0][m] = MFMA(ah, fl0, acc[0][m]);
            acc[0][m] = MFMA(al, fh0, acc[0][m]);
            acc[1][m] = MFMA(ah, fh1, acc[1][m]);
            acc[1][m] = MFMA(ah, fl1, acc[1][m]);
            acc[1][m] = MFMA(al, fh1, acc[1][m]);
        }
    }

    // ---- merge + softmax, one 16-row strip at a time -----------------------
    #pragma unroll
    for (int s = 0; s < 2; ++s) {
        #pragma unroll
        for (int m = 0; m < 5; ++m)
            #pragma unroll
            for (int r = 0; r < 4; ++r)
                S[h][lr][16 * m + 4 * lg + r] = acc[s][m][r];
        __syncthreads();
        {
            const int srow = 4 * h + (lane >> 4), scol = lane & 15;
            float v5[6];
            float mx = -3.0e38f;
            #pragma unroll
            for (int j = 0; j < 6; ++j) {
                const int n = scol + 16 * j;
                float sv = 0.f;
                if (j < 5) {
                    sv = S[0][srow][n] + S[1][srow][n] + S[2][srow][n] + S[3][srow][n];
                    if (n < NW) mx = fmaxf(mx, sv);
                }
                v5[j] = sv;
            }
            mx = fmaxf(mx, __shfl_xor(mx, 1));
            mx = fmaxf(mx, __shfl_xor(mx, 2));
            mx = fmaxf(mx, __shfl_xor(mx, 4));
            mx = fmaxf(mx, __shfl_xor(mx, 8));
            float sum = 0.f;
            #pragma unroll
            for (int j = 0; j < 6; ++j) {
                const int n = scol + 16 * j;
                const float e = (n < NW) ? __expf(v5[j] - mx) : 0.f;
                v5[j] = e; sum += e;
            }
            sum += __shfl_xor(sum, 1);
            sum += __shfl_xor(sum, 2);
            sum += __shfl_xor(sum, 4);
            sum += __shfl_xor(sum, 8);
            const float inv = 1.0f / sum;
            #pragma unroll
            for (int j = 0; j < 6; ++j) {
                const int n = scol + 16 * j;
                u16 ph, pl; split1(v5[j] * inv, ph, pl);
                Ph[16 * s + srow][n] = ph; Pl[16 * s + srow][n] = pl;
            }
        }
        __syncthreads();
    }

    // ---- Phase 3: out^T[kout][c] = weT . P^T; wave h owns kout quarter ----
    bf16x8 pbh[2][3], pbl[2][3];
    #pragma unroll
    for (int s = 0; s < 2; ++s)
        #pragma unroll
        for (int ksn = 0; ksn < 3; ++ksn) {
            pbh[s][ksn] = *(const bf16x8*)&Ph[16 * s + lr][32 * ksn + 8 * lg];
            pbl[s][ksn] = *(const bf16x8*)&Pl[16 * s + lr][32 * ksn + 8 * lg];
        }
    const bf16x8* th = weT_hi + (size_t)b * HW2_ * 12;
    const bf16x8* tl = weT_lo + (size_t)b * HW2_ * 12;
    float* orow0 = out + (size_t)(b * C_ + c0 + lr) * HW2_;
    float* orow1 = orow0 + 16 * HW2_;

    #pragma unroll
    for (int tt = 0; tt < 16; ++tt) {
        const int row = h * 256 + tt * 16 + lr;
        bf16x8 wa[3], wb[3];
        #pragma unroll
        for (int ksn = 0; ksn < 3; ++ksn) {
            wa[ksn] = th[row * 12 + 4 * ksn + lg];
            wb[ksn] = tl[row * 12 + 4 * ksn + lg];
        }
        f32x4 o0 = (f32x4)0.0f, o1 = (f32x4)0.0f;
        #pragma unroll
        for (int ksn = 0; ksn < 3; ++ksn) {
            o0 = MFMA(wa[ksn], pbh[0][ksn], o0);
            o0 = MFMA(wa[ksn], pbl[0][ksn], o0);
            o0 = MFMA(wb[ksn], pbh[0][ksn], o0);
            o1 = MFMA(wa[ksn], pbh[1][ksn], o1);
            o1 = MFMA(wa[ksn], pbl[1][ksn], o1);
            o1 = MFMA(wb[ksn], pbh[1][ksn], o1);
        }
        const int col = h * 256 + tt * 16 + 4 * lg;
        *(float4*)(orow0 + col) = make_float4(o0[0], o0[1], o0[2], o0[3]);
        *(float4*)(orow1 + col) = make_float4(o1[0], o1[1], o1[2], o1[3]);
    }
}

// ---------------------------------------------------------------------------
extern "C" void kernel_launch(void* const* d_in, const int* in_sizes, int n_in,
                              void* d_out, int out_size, void* d_ws, size_t ws_size,
                              hipStream_t stream) {
    (void)in_sizes; (void)n_in; (void)out_size; (void)ws_size;
    const float* feat     = (const float*)d_in[0];
    const float* word_emb = (const float*)d_in[1];
    const float* W_fc     = (const float*)d_in[2];
    const float* b_fc     = (const float*)d_in[3];

    bf16x8* we_hi  = (bf16x8*)d_ws;
    bf16x8* we_lo  = we_hi  + WE_ELN;
    bf16x8* weT_hi = we_lo  + WE_ELN;
    bf16x8* weT_lo = weT_hi + WET_ELN;
    bf16x8* Wh     = weT_lo + WET_ELN;
    bf16x8* Wl     = Wh + W_ELN;
    bf16x8* Eh     = Wl + W_ELN;
    bf16x8* El     = Eh + E_ELN;

    split_pre<<<448, 256, 0, stream>>>(W_fc, word_emb, Wh, Wl, Eh, El);
    we_gemm<<<512, 256, 0, stream>>>(Wh, Wl, Eh, El, b_fc, we_hi, we_lo, weT_hi, weT_lo);
    attn_mfma<<<512, 256, 0, stream>>>(feat, we_hi, we_lo, weT_hi, weT_lo, (float*)d_out);
}